// Round 6
// baseline (6900.422 us; speedup 1.0000x reference)
//
#include <hip/hip_runtime.h>

constexpr int NSTATE = 4096;
constexpr int NOBS   = 128;
constexpr int TSEQ   = 1024;
constexpr int NWG    = 256;   // one workgroup per CU (cooperative: co-resident)
constexpr int NTHR   = 1024;  // 16 waves

// workspace layout (float-slot offsets)
constexpr size_t WS_BT    = 0;                        // Bt[128][4096] f32
constexpr size_t WS_OBS   = (size_t)NOBS * NSTATE;    // obs as int[1024]
constexpr size_t WS_FLAGS = WS_OBS + TSEQ;            // int flags[256] (+pad)
constexpr size_t WS_Y2E   = WS_FLAGS + 512;           // u64 y2e[2][4096] (8B aligned)

__device__ __forceinline__ int agent_ld_i32(const int* p) {
  return __hip_atomic_load(p, __ATOMIC_RELAXED, __HIP_MEMORY_SCOPE_AGENT);
}
__device__ __forceinline__ void agent_st_i32(int* p, int v) {
  __hip_atomic_store(p, v, __ATOMIC_RELAXED, __HIP_MEMORY_SCOPE_AGENT);
}
__device__ __forceinline__ void agent_st_f32(float* p, float v) {
  __hip_atomic_store(p, v, __ATOMIC_RELAXED, __HIP_MEMORY_SCOPE_AGENT);
}
__device__ __forceinline__ unsigned long long agent_ld_u64(const unsigned long long* p) {
  return __hip_atomic_load(p, __ATOMIC_RELAXED, __HIP_MEMORY_SCOPE_AGENT);
}
__device__ __forceinline__ void agent_st_u64(unsigned long long* p, unsigned long long v) {
  __hip_atomic_store(p, v, __ATOMIC_RELAXED, __HIP_MEMORY_SCOPE_AGENT);
}

// One-time barrier (after Bt transpose + bootstrap). Monotone epoch; poison-safe.
__device__ __forceinline__ void grid_bar_full(int* flags, int w, int tid, int epoch) {
  asm volatile("s_waitcnt vmcnt(0)" ::: "memory");
  __syncthreads();
  if (tid == 0) agent_st_i32(&flags[w], epoch);
  if (tid < 64) {
    for (;;) {
      int m0 = agent_ld_i32(&flags[tid]);
      int m1 = agent_ld_i32(&flags[tid + 64]);
      int m2 = agent_ld_i32(&flags[tid + 128]);
      int m3 = agent_ld_i32(&flags[tid + 192]);
      int mn = min(min(m0, m1), min(m2, m3));
      if (__all(mn >= epoch)) break;
    }
  }
  __syncthreads();
}

__global__ __launch_bounds__(NTHR) void hmm_fwd_kernel(
    const float* __restrict__ A,
    const float* __restrict__ B,
    const float* __restrict__ pi,
    const void*  __restrict__ obs_raw,
    float* __restrict__ out,
    float* __restrict__ ws)
{
  const int tid = threadIdx.x;
  const int w   = blockIdx.x;

  float* __restrict__ Bt    = ws + WS_BT;
  int*   __restrict__ obsg  = (int*)(ws + WS_OBS);
  int*   __restrict__ flags = (int*)(ws + WS_FLAGS);
  unsigned long long* __restrict__ y2e = (unsigned long long*)(ws + WS_Y2E); // [2][4096]

  __shared__ int    obs_lds[TSEQ];
  __shared__ float4 red_f[2][16][4];   // [t-parity][wave][c4]
  __shared__ float  fin[16];
  __shared__ int    flag_lds;

  // ---- static work assignment: wg w owns FULL columns [16w, 16w+16) ----
  const int c4   = tid & 3;              // which 4-col group of the wg's 16
  const int rg   = tid >> 2;             // 0..255 row-group (16 rows each)
  const int ibase = rg << 4;
  const int col0  = (w << 4) + (c4 << 2);
  const int wave = tid >> 6;
  const int lane = tid & 63;

  // ---- preload A block: 16 rows x 4 cols (coalesced float4), pin ----
  const float* __restrict__ Abase = A + (size_t)ibase * NSTATE + col0;
  float ar[64];
#pragma unroll
  for (int k = 0; k < 16; ++k) {
    const float4 v = *(const float4*)(Abase + (size_t)k * NSTATE);
    ar[4*k+0] = v.x; ar[4*k+1] = v.y; ar[4*k+2] = v.z; ar[4*k+3] = v.w;
  }
#pragma unroll
  for (int i = 0; i < 64; ++i) asm volatile("" : "+v"(ar[i]));

  // ---- pre-phase: transpose B -> Bt (agent stores), decode obs ----
  for (int e = w * NTHR + tid; e < NOBS * NSTATE; e += NWG * NTHR) {
    const int o = e >> 12;
    const int j = e & (NSTATE - 1);
    agent_st_f32(&Bt[(size_t)o * NSTATE + j], B[(size_t)j * NOBS + o]);
  }
  if (w == 0) {
    if (tid == 0) flag_lds = 0;
    __syncthreads();
    const long long* p64 = (const long long*)obs_raw;
    if (tid < 256) {                      // probe window valid under either layout
      const long long v = p64[tid];
      if (v < 0 || v >= NOBS) atomicOr(&flag_lds, 1);
    }
    __syncthreads();
    const bool is32 = (flag_lds != 0);
    const int* p32 = (const int*)obs_raw;
    agent_st_i32(&obsg[tid], is32 ? p32[tid] : (int)p64[tid]);
  }
  // bootstrap y[0] := pi, tagged epoch 0, slot 0
  if (tid < 16) {
    union { float f; unsigned u; } cv;
    cv.f = pi[(w << 4) + tid];
    agent_st_u64(&y2e[(w << 4) + tid], (unsigned long long)cv.u); // tag 0 in high word
  }
  grid_bar_full(flags, w, tid, 1);

  obs_lds[tid] = obsg[tid];
  __syncthreads();

  // ---- main recursion: tag-polled dataflow, no grid barrier ----
  for (int t = 1; t < TSEQ; ++t) {
    const int bufc = (t - 1) & 1;
    const int bufp = t & 1;
    const int tagc = t - 1;
    const int o = obs_lds[t - 1];
    const float4* __restrict__ Bt4 = (const float4*)(Bt + ((size_t)o << 12));

    float acc0 = 0.f, acc1 = 0.f, acc2 = 0.f, acc3 = 0.f;
    // consume 16 x-rows in two half-blocks of 8 (register-pressure friendly)
#pragma unroll
    for (int h = 0; h < 2; ++h) {
      const int rb = ibase + h * 8;
      const unsigned long long* src = &y2e[(size_t)bufc * NSTATE + rb];
      // issue emission loads BEFORE the poll: their L3 latency hides under it
      const float4 bb0 = Bt4[(rb >> 2) + 0];
      const float4 bb1 = Bt4[(rb >> 2) + 1];
      unsigned long long v0, v1, v2, v3, v4, v5, v6, v7;
      for (;;) {
        v0 = agent_ld_u64(src + 0); v1 = agent_ld_u64(src + 1);
        v2 = agent_ld_u64(src + 2); v3 = agent_ld_u64(src + 3);
        v4 = agent_ld_u64(src + 4); v5 = agent_ld_u64(src + 5);
        v6 = agent_ld_u64(src + 6); v7 = agent_ld_u64(src + 7);
        bool ok = ((int)(v0 >> 32) == tagc) & ((int)(v1 >> 32) == tagc)
                & ((int)(v2 >> 32) == tagc) & ((int)(v3 >> 32) == tagc)
                & ((int)(v4 >> 32) == tagc) & ((int)(v5 >> 32) == tagc)
                & ((int)(v6 >> 32) == tagc) & ((int)(v7 >> 32) == tagc);
        if (ok) break;
      }
      union { unsigned u; float f; } cv;
      float xv;
      const unsigned long long vv[8] = { v0, v1, v2, v3, v4, v5, v6, v7 };
#pragma unroll
      for (int j = 0; j < 8; ++j) {
        cv.u = (unsigned)vv[j];
        const float b = (j < 4) ? (&bb0.x)[j] : (&bb1.x)[j - 4];
        xv = cv.f * b;
        const int k = h * 8 + j;
        acc0 = fmaf(xv, ar[4*k+0], acc0);
        acc1 = fmaf(xv, ar[4*k+1], acc1);
        acc2 = fmaf(xv, ar[4*k+2], acc2);
        acc3 = fmaf(xv, ar[4*k+3], acc3);
      }
    }
    // reduce over the 16 row-groups within this wave (lane bits 2..5)
#pragma unroll
    for (int m = 4; m <= 32; m <<= 1) {
      acc0 += __shfl_xor(acc0, m);
      acc1 += __shfl_xor(acc1, m);
      acc2 += __shfl_xor(acc2, m);
      acc3 += __shfl_xor(acc3, m);
    }
    if ((lane >> 2) == 0) {   // lanes 0..3 hold the wave's sums for c4 = lane
      red_f[bufp][wave][lane & 3] = make_float4(acc0, acc1, acc2, acc3);
    }
    __syncthreads();
    if (tid < 16) {  // funnel: combine 16 wave partials for column 16w+tid
      float s = 0.f;
#pragma unroll
      for (int wv = 0; wv < 16; ++wv) {
        s += (&red_f[bufp][wv][tid >> 2].x)[tid & 3];
      }
      union { float f; unsigned u; } cv;
      cv.f = s;
      agent_st_u64(&y2e[(size_t)bufp * NSTATE + (w << 4) + tid],
                   ((unsigned long long)(unsigned)t << 32) | cv.u);
    }
    // no second barrier: red_f is double-buffered by t-parity
  }

  // ---- final: alpha = y[1023]*Bt[obs[1023]], total sum (wg 0 reports) ----
  if (w == 0) {
    const int o = obs_lds[TSEQ - 1];
    const int tagf = TSEQ - 1;                 // slot 1
    const unsigned long long* src = &y2e[(size_t)1 * NSTATE + 4 * tid];
    const float* bo = Bt + ((size_t)o << 12) + 4 * tid;
    unsigned long long v0, v1, v2, v3;
    for (;;) {
      v0 = agent_ld_u64(src + 0); v1 = agent_ld_u64(src + 1);
      v2 = agent_ld_u64(src + 2); v3 = agent_ld_u64(src + 3);
      bool ok = ((int)(v0 >> 32) == tagf) & ((int)(v1 >> 32) == tagf)
              & ((int)(v2 >> 32) == tagf) & ((int)(v3 >> 32) == tagf);
      if (ok) break;
    }
    union { unsigned u; float f; } c0, c1, c2, c3;
    c0.u = (unsigned)v0; c1.u = (unsigned)v1; c2.u = (unsigned)v2; c3.u = (unsigned)v3;
    float s = c0.f * bo[0] + c1.f * bo[1] + c2.f * bo[2] + c3.f * bo[3];
#pragma unroll
    for (int m = 1; m <= 32; m <<= 1) s += __shfl_xor(s, m);
    if (lane == 0) fin[wave] = s;
    __syncthreads();
    if (tid == 0) {
      float tot = 0.f;
#pragma unroll
      for (int i = 0; i < 16; ++i) tot += fin[i];
      out[0] = tot;
    }
  }
}

extern "C" void kernel_launch(void* const* d_in, const int* in_sizes, int n_in,
                              void* d_out, int out_size, void* d_ws, size_t ws_size,
                              hipStream_t stream) {
  const float* A   = (const float*)d_in[0];
  const float* B   = (const float*)d_in[1];
  const float* pi  = (const float*)d_in[2];
  const void*  obs = d_in[3];
  float* out = (float*)d_out;
  float* ws  = (float*)d_ws;

  void* args[] = { &A, &B, &pi, &obs, &out, &ws };
  hipLaunchCooperativeKernel((void*)hmm_fwd_kernel, dim3(NWG), dim3(NTHR),
                             args, 0, stream);
}

// Round 7
// 4255.289 us; speedup vs baseline: 1.6216x; 1.6216x over previous
//
#include <hip/hip_runtime.h>

constexpr int NSTATE = 4096;
constexpr int NOBS   = 128;
constexpr int TSEQ   = 1024;
constexpr int NWG    = 256;   // one workgroup per CU (cooperative: co-resident)
constexpr int NTHR   = 1024;  // 16 waves

// workspace layout (float-slot offsets)
constexpr size_t WS_BT    = 0;                        // Bt[128][4096] f32
constexpr size_t WS_OBS   = (size_t)NOBS * NSTATE;    // obs as int[1024]
constexpr size_t WS_FLAGS = WS_OBS + TSEQ;            // int flags[256] (+pad)
constexpr size_t WS_Y2E   = WS_FLAGS + 512;           // u64 y2e[2][4096]

// padded x layout in LDS: 16-state rows at stride 20 floats (80 B, 16B-aligned,
// bank-rotated so fragment reads are <=2-way conflicts)
constexpr int XPAD = 20;

__device__ __forceinline__ int agent_ld_i32(const int* p) {
  return __hip_atomic_load(p, __ATOMIC_RELAXED, __HIP_MEMORY_SCOPE_AGENT);
}
__device__ __forceinline__ void agent_st_i32(int* p, int v) {
  __hip_atomic_store(p, v, __ATOMIC_RELAXED, __HIP_MEMORY_SCOPE_AGENT);
}
__device__ __forceinline__ void agent_st_f32(float* p, float v) {
  __hip_atomic_store(p, v, __ATOMIC_RELAXED, __HIP_MEMORY_SCOPE_AGENT);
}
__device__ __forceinline__ unsigned long long agent_ld_u64(const unsigned long long* p) {
  return __hip_atomic_load(p, __ATOMIC_RELAXED, __HIP_MEMORY_SCOPE_AGENT);
}
__device__ __forceinline__ void agent_st_u64(unsigned long long* p, unsigned long long v) {
  __hip_atomic_store(p, v, __ATOMIC_RELAXED, __HIP_MEMORY_SCOPE_AGENT);
}

// One-time barrier (after Bt transpose + bootstrap). Monotone epoch; poison-safe.
__device__ __forceinline__ void grid_bar_full(int* flags, int w, int tid, int epoch) {
  asm volatile("s_waitcnt vmcnt(0)" ::: "memory");
  __syncthreads();
  if (tid == 0) agent_st_i32(&flags[w], epoch);
  if (tid < 64) {
    for (;;) {
      int m0 = agent_ld_i32(&flags[tid]);
      int m1 = agent_ld_i32(&flags[tid + 64]);
      int m2 = agent_ld_i32(&flags[tid + 128]);
      int m3 = agent_ld_i32(&flags[tid + 192]);
      int mn = min(min(m0, m1), min(m2, m3));
      if (__all(mn >= epoch)) break;
    }
  }
  __syncthreads();
}

__global__ __launch_bounds__(NTHR) void hmm_fwd_kernel(
    const float* __restrict__ A,
    const float* __restrict__ B,
    const float* __restrict__ pi,
    const void*  __restrict__ obs_raw,
    float* __restrict__ out,
    float* __restrict__ ws)
{
  const int tid = threadIdx.x;
  const int w   = blockIdx.x;

  float* __restrict__ Bt    = ws + WS_BT;
  int*   __restrict__ obsg  = (int*)(ws + WS_OBS);
  int*   __restrict__ flags = (int*)(ws + WS_FLAGS);
  unsigned long long* __restrict__ y2e = (unsigned long long*)(ws + WS_Y2E); // [2][4096]

  __shared__ float  x_lds[256 * XPAD];   // 20.5 KB, padded
  __shared__ float4 red_f[2][16][4];     // [t-parity][wave][c4]
  __shared__ int    obs_lds[TSEQ];
  __shared__ float  fin[16];
  __shared__ int    flag_lds;

  // ---- static work assignment: wg w owns FULL columns [16w, 16w+16) ----
  const int c4   = tid & 3;              // which 4-col group of the wg's 16
  const int rg   = tid >> 2;             // 0..255 row-group (16 rows each)
  const int ibase = rg << 4;
  const int col0  = (w << 4) + (c4 << 2);
  const int wave = tid >> 6;
  const int lane = tid & 63;

  // ---- preload A block: 16 rows x 4 cols (coalesced float4), pin ----
  const float* __restrict__ Abase = A + (size_t)ibase * NSTATE + col0;
  float ar[64];
#pragma unroll
  for (int k = 0; k < 16; ++k) {
    const float4 v = *(const float4*)(Abase + (size_t)k * NSTATE);
    ar[4*k+0] = v.x; ar[4*k+1] = v.y; ar[4*k+2] = v.z; ar[4*k+3] = v.w;
  }
#pragma unroll
  for (int i = 0; i < 64; ++i) asm volatile("" : "+v"(ar[i]));

  // ---- pre-phase: transpose B -> Bt (agent stores), decode obs ----
  for (int e = w * NTHR + tid; e < NOBS * NSTATE; e += NWG * NTHR) {
    const int o = e >> 12;
    const int j = e & (NSTATE - 1);
    agent_st_f32(&Bt[(size_t)o * NSTATE + j], B[(size_t)j * NOBS + o]);
  }
  if (w == 0) {
    if (tid == 0) flag_lds = 0;
    __syncthreads();
    const long long* p64 = (const long long*)obs_raw;
    if (tid < 256) {                      // probe window valid under either layout
      const long long v = p64[tid];
      if (v < 0 || v >= NOBS) atomicOr(&flag_lds, 1);
    }
    __syncthreads();
    const bool is32 = (flag_lds != 0);
    const int* p32 = (const int*)obs_raw;
    agent_st_i32(&obsg[tid], is32 ? p32[tid] : (int)p64[tid]);
  }
  // bootstrap y[0] := pi, tagged epoch 0, slot 0
  if (tid < 16) {
    union { float f; unsigned u; } cv;
    cv.f = pi[(w << 4) + tid];
    agent_st_u64(&y2e[(w << 4) + tid], (unsigned long long)cv.u); // tag 0 high word
  }
  grid_bar_full(flags, w, tid, 1);

  obs_lds[tid] = obsg[tid];
  __syncthreads();

  // ---- main recursion: fused tag+data dataflow, LDS-staged broadcast ----
  for (int t = 1; t < TSEQ; ++t) {
    const int bufc = (t - 1) & 1;
    const int bufp = t & 1;
    const int tagc = t - 1;
    const int o = obs_lds[t - 1];

    // stage: poll 4 own tagged words, fuse emission multiply, write to LDS
    {
      // emission loads are normal (L1/L2-cacheable) and independent of y2e
      const float4 bb = ((const float4*)(Bt + ((size_t)o << 12)))[tid];
      const unsigned long long* src = &y2e[(size_t)bufc * NSTATE + 4 * tid];
      unsigned long long v0, v1, v2, v3;
      for (;;) {
        v0 = agent_ld_u64(src + 0); v1 = agent_ld_u64(src + 1);
        v2 = agent_ld_u64(src + 2); v3 = agent_ld_u64(src + 3);
        bool ok = ((int)(v0 >> 32) == tagc) & ((int)(v1 >> 32) == tagc)
                & ((int)(v2 >> 32) == tagc) & ((int)(v3 >> 32) == tagc);
        if (ok) break;
      }
      union { unsigned u; float f; } e0, e1, e2, e3;
      e0.u = (unsigned)v0; e1.u = (unsigned)v1;
      e2.u = (unsigned)v2; e3.u = (unsigned)v3;
      float4 xx;
      xx.x = e0.f * bb.x; xx.y = e1.f * bb.y;
      xx.z = e2.f * bb.z; xx.w = e3.f * bb.w;
      *(float4*)(x_lds + (tid >> 2) * XPAD + (tid & 3) * 4) = xx;
    }
    __syncthreads();

    // compute: 16 x-values from LDS (padded, <=2-way conflicts), 64 FMA
    float acc0 = 0.f, acc1 = 0.f, acc2 = 0.f, acc3 = 0.f;
    {
      const float* xbase = x_lds + rg * XPAD;
#pragma unroll
      for (int q = 0; q < 4; ++q) {
        const float4 xv = *(const float4*)(xbase + 4 * q);
        const int k = 4 * q;
        acc0 = fmaf(xv.x, ar[4*(k+0)+0], acc0);
        acc1 = fmaf(xv.x, ar[4*(k+0)+1], acc1);
        acc2 = fmaf(xv.x, ar[4*(k+0)+2], acc2);
        acc3 = fmaf(xv.x, ar[4*(k+0)+3], acc3);
        acc0 = fmaf(xv.y, ar[4*(k+1)+0], acc0);
        acc1 = fmaf(xv.y, ar[4*(k+1)+1], acc1);
        acc2 = fmaf(xv.y, ar[4*(k+1)+2], acc2);
        acc3 = fmaf(xv.y, ar[4*(k+1)+3], acc3);
        acc0 = fmaf(xv.z, ar[4*(k+2)+0], acc0);
        acc1 = fmaf(xv.z, ar[4*(k+2)+1], acc1);
        acc2 = fmaf(xv.z, ar[4*(k+2)+2], acc2);
        acc3 = fmaf(xv.z, ar[4*(k+2)+3], acc3);
        acc0 = fmaf(xv.w, ar[4*(k+3)+0], acc0);
        acc1 = fmaf(xv.w, ar[4*(k+3)+1], acc1);
        acc2 = fmaf(xv.w, ar[4*(k+3)+2], acc2);
        acc3 = fmaf(xv.w, ar[4*(k+3)+3], acc3);
      }
    }
    // reduce over the 16 row-groups within this wave (lane bits 2..5)
#pragma unroll
    for (int m = 4; m <= 32; m <<= 1) {
      acc0 += __shfl_xor(acc0, m);
      acc1 += __shfl_xor(acc1, m);
      acc2 += __shfl_xor(acc2, m);
      acc3 += __shfl_xor(acc3, m);
    }
    if ((lane >> 2) == 0) {   // lanes 0..3 hold the wave's sums for c4 = lane
      red_f[bufp][wave][lane & 3] = make_float4(acc0, acc1, acc2, acc3);
    }
    __syncthreads();
    if (tid < 16) {  // funnel: combine 16 wave partials for column 16w+tid
      float s = 0.f;
#pragma unroll
      for (int wv = 0; wv < 16; ++wv) {
        s += (&red_f[bufp][wv][tid >> 2].x)[tid & 3];
      }
      union { float f; unsigned u; } cv;
      cv.f = s;
      agent_st_u64(&y2e[(size_t)bufp * NSTATE + (w << 4) + tid],
                   ((unsigned long long)(unsigned)t << 32) | cv.u);
    }
    // no extra barrier: x_lds overwrite is gated by the next stage's
    // syncthreads; red_f overwrite is gated by sync after next stage.
  }

  // ---- final: alpha = y[1023]*Bt[obs[1023]], total sum (wg 0 reports) ----
  if (w == 0) {
    const int o = obs_lds[TSEQ - 1];
    const int tagf = TSEQ - 1;                 // slot 1
    const unsigned long long* src = &y2e[(size_t)1 * NSTATE + 4 * tid];
    const float* bo = Bt + ((size_t)o << 12) + 4 * tid;
    unsigned long long v0, v1, v2, v3;
    for (;;) {
      v0 = agent_ld_u64(src + 0); v1 = agent_ld_u64(src + 1);
      v2 = agent_ld_u64(src + 2); v3 = agent_ld_u64(src + 3);
      bool ok = ((int)(v0 >> 32) == tagf) & ((int)(v1 >> 32) == tagf)
              & ((int)(v2 >> 32) == tagf) & ((int)(v3 >> 32) == tagf);
      if (ok) break;
    }
    union { unsigned u; float f; } c0, c1, c2, c3;
    c0.u = (unsigned)v0; c1.u = (unsigned)v1; c2.u = (unsigned)v2; c3.u = (unsigned)v3;
    float s = c0.f * bo[0] + c1.f * bo[1] + c2.f * bo[2] + c3.f * bo[3];
#pragma unroll
    for (int m = 1; m <= 32; m <<= 1) s += __shfl_xor(s, m);
    if (lane == 0) fin[wave] = s;
    __syncthreads();
    if (tid == 0) {
      float tot = 0.f;
#pragma unroll
      for (int i = 0; i < 16; ++i) tot += fin[i];
      out[0] = tot;
    }
  }
}

extern "C" void kernel_launch(void* const* d_in, const int* in_sizes, int n_in,
                              void* d_out, int out_size, void* d_ws, size_t ws_size,
                              hipStream_t stream) {
  const float* A   = (const float*)d_in[0];
  const float* B   = (const float*)d_in[1];
  const float* pi  = (const float*)d_in[2];
  const void*  obs = d_in[3];
  float* out = (float*)d_out;
  float* ws  = (float*)d_ws;

  void* args[] = { &A, &B, &pi, &obs, &out, &ws };
  hipLaunchCooperativeKernel((void*)hmm_fwd_kernel, dim3(NWG), dim3(NTHR),
                             args, 0, stream);
}